// Round 5
// baseline (196.707 us; speedup 1.0000x reference)
//
#include <hip/hip_runtime.h>
#include <hip/hip_bf16.h>

#define N2    16384
#define NHALF 8192
#define KDIM  128
#define BCOL  128      // cols per iteration per quarter
#define NQUARTER 4096  // cols per (block,quarter)
#define NITER (NQUARTER / BCOL)   // 32

using bf16x8 = __attribute__((ext_vector_type(8))) short;
using f32x4  = __attribute__((ext_vector_type(4))) float;

#if __has_builtin(__builtin_amdgcn_exp2f)
#define EXP2F(x) __builtin_amdgcn_exp2f(x)
#else
#define EXP2F(x) exp2f(x)
#endif
#if __has_builtin(__builtin_amdgcn_logf)
#define LOG2F(x) __builtin_amdgcn_logf(x)
#else
#define LOG2F(x) log2f(x)
#endif

// exp(2*dot) == exp2(dot * 2*log2(e)); we fold sqrt(2*log2(e)) into each z
// at convert time so the MFMA result is already in exp2 domain.
#define PRESCALE 1.6986436005760381f   // sqrt(2*log2(e))

__device__ __forceinline__ unsigned short f2bf(float f) {
  unsigned u = __float_as_uint(f);
  u += 0x7fffu + ((u >> 16) & 1u);   // RNE
  return (unsigned short)(u >> 16);
}

// ---- K1: f32 -> bf16 conversion with PRESCALE (z -> zb) + zero S and out ----
__global__ void k_convert(const float* __restrict__ z, unsigned short* __restrict__ zb,
                          float* __restrict__ S, float* __restrict__ out) {
  int i = blockIdx.x * blockDim.x + threadIdx.x;  // over N2*KDIM/4
  if (i < N2) S[i] = 0.f;
  if (i == 0) out[0] = 0.f;
  float4 v = reinterpret_cast<const float4*>(z)[i];
  ushort4 o;
  o.x = f2bf(v.x * PRESCALE); o.y = f2bf(v.y * PRESCALE);
  o.z = f2bf(v.z * PRESCALE); o.w = f2bf(v.w * PRESCALE);
  reinterpret_cast<ushort4*>(zb)[i] = o;
}

// ---- K2: fused sim -> exp -> row sums (diagonal masked) ----
// R5: BARRIER-FREE, LDS-FREE. zb is 4 MB bf16 = fits a single XCD's L2, so
// LDS staging of B was pure overhead (DMA + vmcnt(0) drains + per-tile
// barriers locking the CU's waves into the same phase: MfmaUtil ~30% while
// the MFMA work itself needs 33 us/SIMD). Occupancy experiments showed
// 2x8-wave blocks never reliably co-reside (R3 spill at forced cap, R4 still
// 21% occupancy at VGPR=72) -> abandon block-level co-residency; shrink to
// 256-thread blocks (4 waves) with NO __shared__ and NO __syncthreads.
// grid = 1024: (row-group rg = bx>>2, 64 rows) x (col quarter = bx&3).
// Wave w in [0,4) covers a 32-col strip per iteration; per iter it loads its
// 8 B-fragments straight from zb (B-fragment layout == A-fragment layout
// since sim = zb.zb^T: lane c15 = col, q*8 = k; one bf16x8 at
// bp + n*16*KDIM + s*32, imm offsets <= 4288B, one pointer += per iter).
// Every 64B line is fully consumed; the B region is L2-resident so the
// ~1 GB of B re-reads ride the 34.5 TB/s L2, overlapped with MFMA.
// 4 blocks/CU = 4 waves/SIMD, free-running -> waves drift out of phase and
// one wave's MFMA chains cover another's exp2/load latency.
__global__ __launch_bounds__(256, 4) void k_main(const unsigned short* __restrict__ zb,
                                                 float* __restrict__ S) {
  const int t    = threadIdx.x;
  const int w    = t >> 6;    // 32-col strip within the current 128-col group
  const int l    = t & 63;
  const int q    = l >> 4;    // quad within wave
  const int c15  = l & 15;
  const int rg      = blockIdx.x >> 2;
  const int quarter = blockIdx.x & 3;
  const int rbase = rg * 64;

  // A fragments: a-frag layout (16x16x32): lane holds A[m=lane&15][k=q*8+j]
  bf16x8 afr[4][4];
#pragma unroll
  for (int m = 0; m < 4; ++m) {
    const unsigned short* ap = zb + (size_t)(rbase + m * 16 + c15) * KDIM + q * 8;
#pragma unroll
    for (int s = 0; s < 4; ++s)
      afr[m][s] = *reinterpret_cast<const bf16x8*>(ap + s * 32);
  }

  float rowsum[4][4];
#pragma unroll
  for (int m = 0; m < 4; ++m)
#pragma unroll
    for (int r = 0; r < 4; ++r) rowsum[m][r] = 0.f;

  // Per-lane B pointer: col = quarter*NQUARTER + it*BCOL + w*32 + n*16 + c15,
  // element k = s*32 + q*8 + j. Advances by BCOL*KDIM per iteration.
  const unsigned short* bp =
      zb + (size_t)(quarter * NQUARTER + w * 32 + c15) * KDIM + q * 8;
  // Diagonal fragment condition: global row = rbase + m*16 + q*4 + r,
  // global col = (C0 + w*32) + n*16 + c15. Fragment (m,n) touches the
  // diagonal iff dOff == (m-n)*16; element masked when c15 == q*4+r.
  int dOff = (quarter * NQUARTER + w * 32) - rbase;

  for (int it = 0; it < NITER; ++it) {
    // 8 direct global loads (L2-hit); imm offsets n*4096B + s*64B.
    bf16x8 bfr[4][2];   // [s][n]
#pragma unroll
    for (int n = 0; n < 2; ++n)
#pragma unroll
      for (int s = 0; s < 4; ++s)
        bfr[s][n] = *reinterpret_cast<const bf16x8*>(bp + n * 16 * KDIM + s * 32);

    // Chain-major: per (m,n) output fragment, run the serial K-chain then
    // immediately its epilogue (keeps only one f32x4 acc live -> low VGPR).
#pragma unroll
    for (int m = 0; m < 4; ++m)
#pragma unroll
      for (int n = 0; n < 2; ++n) {
        f32x4 acc = (f32x4){0.f, 0.f, 0.f, 0.f};
#pragma unroll
        for (int s = 0; s < 4; ++s)
          acc = __builtin_amdgcn_mfma_f32_16x16x32_bf16(afr[m][s], bfr[s][n], acc, 0, 0, 0);
        const bool dfrag = (dOff == (m - n) * 16);  // wave-uniform
#pragma unroll
        for (int r = 0; r < 4; ++r) {
          float e = EXP2F(acc[r]);
          if (dfrag && (c15 == q * 4 + r)) e = 0.f;  // sim[i][i] masked
          rowsum[m][r] += e;
        }
      }

    bp   += (size_t)BCOL * KDIM;
    dOff += BCOL;
  }

  // reduce across 16 column-lanes (xor 1,2,4,8 stay within quads), then one
  // atomicAdd per row-partial (16 per S element: 4 quarters x 4 strips)
#pragma unroll
  for (int m = 0; m < 4; ++m)
#pragma unroll
    for (int r = 0; r < 4; ++r) {
      float v = rowsum[m][r];
      v += __shfl_xor(v, 1);
      v += __shfl_xor(v, 2);
      v += __shfl_xor(v, 4);
      v += __shfl_xor(v, 8);
      if (c15 == 0) atomicAdd(&S[rbase + m * 16 + q * 4 + r], v);
    }
}

// ---- K3: loss_i = log(S_i) - 2*z_i.z_pair(i); mean into out ----
__global__ void k_final(const float* __restrict__ z, const float* __restrict__ S,
                        float* __restrict__ out) {
  __shared__ float red[256];
  int t = threadIdx.x;
  int i = blockIdx.x * 256 + t;
  int j = i ^ NHALF;  // positive pair index
  const float4* zi = reinterpret_cast<const float4*>(z + (size_t)i * KDIM);
  const float4* zj = reinterpret_cast<const float4*>(z + (size_t)j * KDIM);
  float dot = 0.f;
#pragma unroll
  for (int k = 0; k < KDIM / 4; ++k) {
    float4 a = zi[k], b = zj[k];
    dot += a.x * b.x + a.y * b.y + a.z * b.z + a.w * b.w;
  }
  float loss = LOG2F(S[i]) * 0.69314718055994531f - 2.f * dot;
  red[t] = loss;
  __syncthreads();
  for (int o = 128; o > 0; o >>= 1) {
    if (t < o) red[t] += red[t + o];
    __syncthreads();
  }
  if (t == 0) atomicAdd(out, red[0] * (1.f / N2));
}

extern "C" void kernel_launch(void* const* d_in, const int* in_sizes, int n_in,
                              void* d_out, int out_size, void* d_ws, size_t ws_size,
                              hipStream_t stream) {
  const float* z = (const float*)d_in[0];
  float* out = (float*)d_out;
  unsigned short* zb = (unsigned short*)d_ws;                       // 4 MB bf16 copy of z
  float* S = (float*)((char*)d_ws + (size_t)N2 * KDIM * 2);         // 64 KB row sums

  k_convert<<<(N2 * KDIM / 4) / 256, 256, 0, stream>>>(z, zb, S, out);
  k_main<<<(N2 / 64) * 4, 256, 0, stream>>>(zb, S);
  k_final<<<N2 / 256, 256, 0, stream>>>(z, S, out);
}

// Round 6
// 195.294 us; speedup vs baseline: 1.0072x; 1.0072x over previous
//
#include <hip/hip_runtime.h>
#include <hip/hip_bf16.h>

#define N2    16384
#define NHALF 8192
#define KDIM  128
#define BCOL  128      // cols per iteration per quarter
#define NQUARTER 4096  // cols per (block,quarter)
#define NITER (NQUARTER / BCOL)   // 32 (even; loop unrolled by 2)

using bf16x8 = __attribute__((ext_vector_type(8))) short;
using f32x4  = __attribute__((ext_vector_type(4))) float;

#if __has_builtin(__builtin_amdgcn_exp2f)
#define EXP2F(x) __builtin_amdgcn_exp2f(x)
#else
#define EXP2F(x) exp2f(x)
#endif
#if __has_builtin(__builtin_amdgcn_logf)
#define LOG2F(x) __builtin_amdgcn_logf(x)
#else
#define LOG2F(x) log2f(x)
#endif

// exp(2*dot) == exp2(dot * 2*log2(e)); we fold sqrt(2*log2(e)) into each z
// at convert time so the MFMA result is already in exp2 domain.
#define PRESCALE 1.6986436005760381f   // sqrt(2*log2(e))

__device__ __forceinline__ unsigned short f2bf(float f) {
  unsigned u = __float_as_uint(f);
  u += 0x7fffu + ((u >> 16) & 1u);   // RNE
  return (unsigned short)(u >> 16);
}

// ---- K1: f32 -> bf16 conversion with PRESCALE (z -> zb) + zero S and out ----
__global__ void k_convert(const float* __restrict__ z, unsigned short* __restrict__ zb,
                          float* __restrict__ S, float* __restrict__ out) {
  int i = blockIdx.x * blockDim.x + threadIdx.x;  // over N2*KDIM/4
  if (i < N2) S[i] = 0.f;
  if (i == 0) out[0] = 0.f;
  float4 v = reinterpret_cast<const float4*>(z)[i];
  ushort4 o;
  o.x = f2bf(v.x * PRESCALE); o.y = f2bf(v.y * PRESCALE);
  o.z = f2bf(v.z * PRESCALE); o.w = f2bf(v.w * PRESCALE);
  reinterpret_cast<ushort4*>(zb)[i] = o;
}

// Load one iteration's B fragments (8 x 16B, L2-hit; layout == A-frag layout
// since sim = zb.zb^T: lane c15 = col-within-16, q*8 = k offset).
__device__ __forceinline__ void loadB(bf16x8 (&dst)[4][2], const unsigned short* p) {
#pragma unroll
  for (int n = 0; n < 2; ++n)
#pragma unroll
    for (int s = 0; s < 4; ++s)
      dst[s][n] = *reinterpret_cast<const bf16x8*>(p + n * 16 * KDIM + s * 32);
}

// One 64x128 tile: 32 MFMAs in S-MAJOR order (8 independent MFMAs between
// dependent accumulator pairs -> fully pipelined issue, ~5cyc/MFMA, vs
// chain-major's ~19cyc latency-serialized issue — the R1/R5 regression),
// then the exp2/mask/rowsum epilogue.
__device__ __forceinline__ void computeTile(const bf16x8 (&afr)[4][4],
                                            const bf16x8 (&bfr)[4][2],
                                            float (&rowsum)[4][4],
                                            int dOff, int q, int c15) {
  f32x4 acc[4][2];
#pragma unroll
  for (int m = 0; m < 4; ++m)
#pragma unroll
    for (int n = 0; n < 2; ++n) acc[m][n] = (f32x4){0.f, 0.f, 0.f, 0.f};
#pragma unroll
  for (int s = 0; s < 4; ++s)
#pragma unroll
    for (int m = 0; m < 4; ++m)
#pragma unroll
      for (int n = 0; n < 2; ++n)
        acc[m][n] = __builtin_amdgcn_mfma_f32_16x16x32_bf16(afr[m][s], bfr[s][n],
                                                            acc[m][n], 0, 0, 0);
  // Diagonal: global row = rbase + m*16 + q*4 + r, col = C0 + n*16 + c15.
  // Fragment (m,n) touches the diagonal iff dOff == (m-n)*16; element masked
  // when c15 == q*4+r.
#pragma unroll
  for (int m = 0; m < 4; ++m)
#pragma unroll
    for (int n = 0; n < 2; ++n) {
      const bool dfrag = (dOff == (m - n) * 16);  // wave-uniform
#pragma unroll
      for (int r = 0; r < 4; ++r) {
        float e = EXP2F(acc[m][n][r]);
        if (dfrag && (c15 == q * 4 + r)) e = 0.f;  // sim[i][i] masked
        rowsum[m][r] += e;
      }
    }
}

// ---- K2: fused sim -> exp -> row sums (diagonal masked) ----
// R6: barrier-free L2-direct (R5 concept) with R5's two mechanical failures
// fixed, per counters:
//  (1) R5's launch_bounds(256,4) VGPR=64 + zero scratch traffic = compiler
//      REMATERIALIZED afr from L2 inside the loop (zb is const restrict) ->
//      ~24 L2 loads/iter on the critical path, MfmaUtil 20%. Fix: (256,2)
//      gives the 256-VGPR budget; the ~190-reg live set stays resident.
//  (2) chain-major's 4-deep dependent MFMA chains serialize issue at the
//      ~16-20cyc MFMA latency (also why R1 < R0). Fix: s-major + acc[4][2].
// Plus explicit register double-buffering of B: iter k+1's 8 fragments are
// issued before computing iter k (load-to-use distance ~one tile >> L2
// latency); loop unrolled by 2 with named bA/bB so all indexing is static.
// No __shared__, no __syncthreads: 2 free-running waves/SIMD whose MFMA and
// exp2 phases drift and overlap across matrix/trans pipes.
__global__ __launch_bounds__(256, 2) void k_main(const unsigned short* __restrict__ zb,
                                                 float* __restrict__ S) {
  const int t    = threadIdx.x;
  const int w    = t >> 6;    // 32-col strip within the current 128-col group
  const int l    = t & 63;
  const int q    = l >> 4;    // quad within wave
  const int c15  = l & 15;
  const int rg      = blockIdx.x >> 2;
  const int quarter = blockIdx.x & 3;
  const int rbase = rg * 64;

  // A fragments resident for the whole kernel: lane holds A[m=lane&15][k=q*8+j]
  bf16x8 afr[4][4];
#pragma unroll
  for (int m = 0; m < 4; ++m) {
    const unsigned short* ap = zb + (size_t)(rbase + m * 16 + c15) * KDIM + q * 8;
#pragma unroll
    for (int s = 0; s < 4; ++s)
      afr[m][s] = *reinterpret_cast<const bf16x8*>(ap + s * 32);
  }

  float rowsum[4][4];
#pragma unroll
  for (int m = 0; m < 4; ++m)
#pragma unroll
    for (int r = 0; r < 4; ++r) rowsum[m][r] = 0.f;

  // Per-lane B pointer: col = quarter*NQUARTER + it*BCOL + w*32 + n*16 + c15,
  // element k = s*32 + q*8 + j.
  const unsigned short* bp =
      zb + (size_t)(quarter * NQUARTER + w * 32 + c15) * KDIM + q * 8;
  int dOff = (quarter * NQUARTER + w * 32) - rbase;

  bf16x8 bA[4][2], bB[4][2];
  loadB(bA, bp);                                   // prologue: iter 0
  for (int it = 0; it < NITER; it += 2) {
    loadB(bB, bp + (size_t)BCOL * KDIM);           // prefetch iter it+1
    computeTile(afr, bA, rowsum, dOff, q, c15);
    if (it + 2 < NITER)
      loadB(bA, bp + (size_t)2 * BCOL * KDIM);     // prefetch iter it+2
    computeTile(afr, bB, rowsum, dOff + BCOL, q, c15);
    bp   += (size_t)2 * BCOL * KDIM;
    dOff += 2 * BCOL;
  }

  // reduce across 16 column-lanes (xor 1,2,4,8 stay within quads), then one
  // atomicAdd per row-partial (16 per S element: 4 quarters x 4 strips)
#pragma unroll
  for (int m = 0; m < 4; ++m)
#pragma unroll
    for (int r = 0; r < 4; ++r) {
      float v = rowsum[m][r];
      v += __shfl_xor(v, 1);
      v += __shfl_xor(v, 2);
      v += __shfl_xor(v, 4);
      v += __shfl_xor(v, 8);
      if (c15 == 0) atomicAdd(&S[rbase + m * 16 + q * 4 + r], v);
    }
}

// ---- K3: loss_i = log(S_i) - 2*z_i.z_pair(i); mean into out ----
__global__ void k_final(const float* __restrict__ z, const float* __restrict__ S,
                        float* __restrict__ out) {
  __shared__ float red[256];
  int t = threadIdx.x;
  int i = blockIdx.x * 256 + t;
  int j = i ^ NHALF;  // positive pair index
  const float4* zi = reinterpret_cast<const float4*>(z + (size_t)i * KDIM);
  const float4* zj = reinterpret_cast<const float4*>(z + (size_t)j * KDIM);
  float dot = 0.f;
#pragma unroll
  for (int k = 0; k < KDIM / 4; ++k) {
    float4 a = zi[k], b = zj[k];
    dot += a.x * b.x + a.y * b.y + a.z * b.z + a.w * b.w;
  }
  float loss = LOG2F(S[i]) * 0.69314718055994531f - 2.f * dot;
  red[t] = loss;
  __syncthreads();
  for (int o = 128; o > 0; o >>= 1) {
    if (t < o) red[t] += red[t + o];
    __syncthreads();
  }
  if (t == 0) atomicAdd(out, red[0] * (1.f / N2));
}

extern "C" void kernel_launch(void* const* d_in, const int* in_sizes, int n_in,
                              void* d_out, int out_size, void* d_ws, size_t ws_size,
                              hipStream_t stream) {
  const float* z = (const float*)d_in[0];
  float* out = (float*)d_out;
  unsigned short* zb = (unsigned short*)d_ws;                       // 4 MB bf16 copy of z
  float* S = (float*)((char*)d_ws + (size_t)N2 * KDIM * 2);         // 64 KB row sums

  k_convert<<<(N2 * KDIM / 4) / 256, 256, 0, stream>>>(z, zb, S, out);
  k_main<<<(N2 / 64) * 4, 256, 0, stream>>>(zb, S);
  k_final<<<N2 / 256, 256, 0, stream>>>(z, S, out);
}

// Round 7
// 146.248 us; speedup vs baseline: 1.3450x; 1.3354x over previous
//
#include <hip/hip_runtime.h>
#include <hip/hip_bf16.h>

#define N2    16384
#define NHALF 8192
#define KDIM  128
#define WCOLS 32                  // cols per wave-strip per iteration
#define BCOLS 128                 // cols per block per iteration (4 waves)
#define NHCOL 8192                // cols per block (half of N2)
#define NITER (NHCOL / BCOLS)     // 64

using bf16x8 = __attribute__((ext_vector_type(8))) short;
using f32x4  = __attribute__((ext_vector_type(4))) float;

#if __has_builtin(__builtin_amdgcn_exp2f)
#define EXP2F(x) __builtin_amdgcn_exp2f(x)
#else
#define EXP2F(x) exp2f(x)
#endif
#if __has_builtin(__builtin_amdgcn_logf)
#define LOG2F(x) __builtin_amdgcn_logf(x)
#else
#define LOG2F(x) log2f(x)
#endif

// exp(2*dot) == exp2(dot * 2*log2(e)); we fold sqrt(2*log2(e)) into each z
// at convert time so the MFMA result is already in exp2 domain.
#define PRESCALE 1.6986436005760381f   // sqrt(2*log2(e))

typedef const __attribute__((address_space(1))) void* gas_ptr;
typedef __attribute__((address_space(3))) void* las_ptr;

__device__ __forceinline__ unsigned short f2bf(float f) {
  unsigned u = __float_as_uint(f);
  u += 0x7fffu + ((u >> 16) & 1u);   // RNE
  return (unsigned short)(u >> 16);
}

// ---- K1: f32 -> bf16 conversion with PRESCALE (z -> zb) + zero S and out ----
__global__ void k_convert(const float* __restrict__ z, unsigned short* __restrict__ zb,
                          float* __restrict__ S, float* __restrict__ out) {
  int i = blockIdx.x * blockDim.x + threadIdx.x;  // over N2*KDIM/4
  if (i < N2) S[i] = 0.f;
  if (i == 0) out[0] = 0.f;
  float4 v = reinterpret_cast<const float4*>(z)[i];
  ushort4 o;
  o.x = f2bf(v.x * PRESCALE); o.y = f2bf(v.y * PRESCALE);
  o.z = f2bf(v.z * PRESCALE); o.w = f2bf(v.w * PRESCALE);
  reinterpret_cast<ushort4*>(zb)[i] = o;
}

// ---- K2: fused sim -> exp -> row sums (diagonal masked) ----
// R7: BARRIER-FREE with PER-WAVE PRIVATE LDS SLICES + COUNTED VMCNT.
// Evidence trail: LDS-staged R0 (79.6us) beat all L2-direct variants
// (R5/R6: 138-139us — compiler rematerialized the loop-invariant afr loads
// from L2 (VGPR=108 vs ~190 live) putting ~24 L2 loads/iter on the critical
// path). R0's own limiter was the 8-wave lockstep __syncthreads (MfmaUtil 34%).
// This version removes BOTH:
//  - B staging stays DMA->LDS (no VGPR pressure, no remat incentive), but
//    each wave owns a private 2 x 8 KB slice: only it writes/reads it, so
//    there is NO __syncthreads anywhere. Per-wave sync = counted
//    s_waitcnt vmcnt(8): issue next tile's 8 DMAs, wait only for the
//    previous 8 (T4 pattern), compute. Waves free-run out of phase ->
//    matrix/trans/LDS pipes overlap across the CU's 8 resident waves.
//  - afr is pinned via asm volatile("" : "+v") after load: asm-defined
//    values cannot be rematerialized; A stays in registers for the kernel.
// Geometry: 256-thr blocks = 4 waves x 32-col strips over 64 shared rows.
// grid = 512 (256 row-groups x 2 col-halves) -> exactly 2 blocks/CU
// (2 x 64 KiB LDS), whole grid resident, no tail.
// Swizzle: data granule (row,k8) stored at physical granule (row,k8^(row&15)),
// applied on DMA *source* addresses (dest is lane-linear); read back with the
// same XOR -> bank math identical to R0 (measured SQ_LDS_BANK_CONFLICT==0).
__global__ __launch_bounds__(256, 2) void k_main(const unsigned short* __restrict__ zb,
                                                 float* __restrict__ S) {
  __shared__ __align__(16) unsigned short Bs[4][2][WCOLS * KDIM];  // 64 KiB
  const int t    = threadIdx.x;
  const int w    = t >> 6;    // wave = 32-col strip
  const int l    = t & 63;
  const int q    = l >> 4;    // quad within wave
  const int c15  = l & 15;
  const int rg   = blockIdx.x >> 1;
  const int half = blockIdx.x & 1;
  const int rbase = rg * 64;

  // Per-lane DMA source byte offsets within the wave's 8 KB strip, for 8
  // issues. Physical granule p = j*64 + l; row=p>>4 (16 granules/row), pg=p&15;
  // source data granule k8 = pg ^ (row&15).
  int srcoff[8];
#pragma unroll
  for (int j = 0; j < 8; ++j) {
    int p   = j * 64 + l;
    int row = p >> 4;
    int pg  = p & 15;
    int k8  = pg ^ (row & 15);
    srcoff[j] = (row * 16 + k8) * 16;   // bytes
  }

  // Strip source base: cols [half*NHCOL + w*WCOLS + it*BCOLS, +32) = 32
  // consecutive zb rows = 8 KB contiguous per iteration.
  const char* sbase = (const char*)zb + (size_t)(half * NHCOL + w * WCOLS) * KDIM * 2;

  // Prologue: DMA iter 0 into buffer 0 (8 issues, vmcnt +8).
#pragma unroll
  for (int j = 0; j < 8; ++j)
    __builtin_amdgcn_global_load_lds((gas_ptr)(sbase + srcoff[j]),
                                     (las_ptr)(&Bs[w][0][j * 512]), 16, 0, 0);

  // A fragments (a-frag layout 16x16x32: lane holds A[m=lane&15][k=q*8+j]),
  // then PIN each in registers (asm-defined => not rematerializable).
  bf16x8 afr[4][4];
#pragma unroll
  for (int m = 0; m < 4; ++m) {
    const unsigned short* ap = zb + (size_t)(rbase + m * 16 + c15) * KDIM + q * 8;
#pragma unroll
    for (int s = 0; s < 4; ++s)
      afr[m][s] = *reinterpret_cast<const bf16x8*>(ap + s * 32);
  }
#pragma unroll
  for (int m = 0; m < 4; ++m)
#pragma unroll
    for (int s = 0; s < 4; ++s)
      asm volatile("" : "+v"(afr[m][s]));

  float rowsum[4][4];
#pragma unroll
  for (int m = 0; m < 4; ++m)
#pragma unroll
    for (int r = 0; r < 4; ++r) rowsum[m][r] = 0.f;

  const int dOff0 = (half * NHCOL + w * WCOLS) - rbase;

  for (int it = 0; it < NITER; ++it) {
    const int buf = it & 1;
    // Issue next tile's DMA into the other buffer, then wait ONLY for the
    // current tile's 8 loads (counted vmcnt — never a full drain mid-loop).
    if (it + 1 < NITER) {
      const char* src = sbase + (size_t)(it + 1) * BCOLS * KDIM * 2;
#pragma unroll
      for (int j = 0; j < 8; ++j)
        __builtin_amdgcn_global_load_lds((gas_ptr)(src + srcoff[j]),
                                         (las_ptr)(&Bs[w][buf ^ 1][j * 512]), 16, 0, 0);
      asm volatile("s_waitcnt vmcnt(8)" ::: "memory");
    } else {
      asm volatile("s_waitcnt vmcnt(0)" ::: "memory");
    }

    // 8 swizzled ds_read_b128: B[col=n*16+c15][k=s*32+q*8..+8]; physical
    // granule pg = (s*4+q) ^ c15 (verified conflict-free pattern).
    bf16x8 bfr[4][2];   // [s][n]
#pragma unroll
    for (int s = 0; s < 4; ++s)
#pragma unroll
      for (int n = 0; n < 2; ++n) {
        int idx = (n * 16 + c15) * KDIM + (((s * 4 + q) ^ c15) * 8);
        bfr[s][n] = *reinterpret_cast<const bf16x8*>(&Bs[w][buf][idx]);
      }

    // s-major MFMA (8 independent chains interleaved -> pipelined issue).
    f32x4 acc[4][2];
#pragma unroll
    for (int m = 0; m < 4; ++m)
#pragma unroll
      for (int n = 0; n < 2; ++n) acc[m][n] = (f32x4){0.f, 0.f, 0.f, 0.f};
#pragma unroll
    for (int s = 0; s < 4; ++s)
#pragma unroll
      for (int m = 0; m < 4; ++m)
#pragma unroll
        for (int n = 0; n < 2; ++n)
          acc[m][n] = __builtin_amdgcn_mfma_f32_16x16x32_bf16(afr[m][s], bfr[s][n],
                                                              acc[m][n], 0, 0, 0);

    // Epilogue: exp2 (inputs pre-scaled) + diagonal mask + row-sum.
    // Fragment (m,n): global row = rbase+m*16+q*4+r, col = C0+n*16+c15;
    // diagonal iff dOff == (m-n)*16, element masked when c15 == q*4+r.
    const int dOff = dOff0 + it * BCOLS;
#pragma unroll
    for (int m = 0; m < 4; ++m)
#pragma unroll
      for (int n = 0; n < 2; ++n) {
        const bool dfrag = (dOff == (m - n) * 16);  // wave-uniform
#pragma unroll
        for (int r = 0; r < 4; ++r) {
          float e = EXP2F(acc[m][n][r]);
          if (dfrag && (c15 == q * 4 + r)) e = 0.f;  // sim[i][i] masked
          rowsum[m][r] += e;
        }
      }
  }

  // reduce across 16 column-lanes (xor 1,2,4,8 stay within quads), then one
  // atomicAdd per row-partial (8 per S element: 2 halves x 4 strips)
#pragma unroll
  for (int m = 0; m < 4; ++m)
#pragma unroll
    for (int r = 0; r < 4; ++r) {
      float v = rowsum[m][r];
      v += __shfl_xor(v, 1);
      v += __shfl_xor(v, 2);
      v += __shfl_xor(v, 4);
      v += __shfl_xor(v, 8);
      if (c15 == 0) atomicAdd(&S[rbase + m * 16 + q * 4 + r], v);
    }
}

// ---- K3: loss_i = log(S_i) - 2*z_i.z_pair(i); mean into out ----
__global__ void k_final(const float* __restrict__ z, const float* __restrict__ S,
                        float* __restrict__ out) {
  __shared__ float red[256];
  int t = threadIdx.x;
  int i = blockIdx.x * 256 + t;
  int j = i ^ NHALF;  // positive pair index
  const float4* zi = reinterpret_cast<const float4*>(z + (size_t)i * KDIM);
  const float4* zj = reinterpret_cast<const float4*>(z + (size_t)j * KDIM);
  float dot = 0.f;
#pragma unroll
  for (int k = 0; k < KDIM / 4; ++k) {
    float4 a = zi[k], b = zj[k];
    dot += a.x * b.x + a.y * b.y + a.z * b.z + a.w * b.w;
  }
  float loss = LOG2F(S[i]) * 0.69314718055994531f - 2.f * dot;
  red[t] = loss;
  __syncthreads();
  for (int o = 128; o > 0; o >>= 1) {
    if (t < o) red[t] += red[t + o];
    __syncthreads();
  }
  if (t == 0) atomicAdd(out, red[0] * (1.f / N2));
}

extern "C" void kernel_launch(void* const* d_in, const int* in_sizes, int n_in,
                              void* d_out, int out_size, void* d_ws, size_t ws_size,
                              hipStream_t stream) {
  const float* z = (const float*)d_in[0];
  float* out = (float*)d_out;
  unsigned short* zb = (unsigned short*)d_ws;                       // 4 MB bf16 copy of z
  float* S = (float*)((char*)d_ws + (size_t)N2 * KDIM * 2);         // 64 KB row sums

  k_convert<<<(N2 * KDIM / 4) / 256, 256, 0, stream>>>(z, zb, S, out);
  k_main<<<(N2 / 64) * 2, 256, 0, stream>>>(zb, S);
  k_final<<<N2 / 256, 256, 0, stream>>>(z, S, out);
}

// Round 8
// 144.460 us; speedup vs baseline: 1.3617x; 1.0124x over previous
//
#include <hip/hip_runtime.h>
#include <hip/hip_bf16.h>

#define N2    16384
#define NHALF 8192
#define KDIM  128
#define WCOLS 32                  // cols per wave-strip per iteration
#define BCOLS 128                 // cols per block per iteration (4 waves)
#define NHCOL 8192                // cols per block (half of N2)
#define NITER (NHCOL / BCOLS)     // 64

using bf16x8 = __attribute__((ext_vector_type(8))) short;
using f32x4  = __attribute__((ext_vector_type(4))) float;

#if __has_builtin(__builtin_amdgcn_exp2f)
#define EXP2F(x) __builtin_amdgcn_exp2f(x)
#else
#define EXP2F(x) exp2f(x)
#endif
#if __has_builtin(__builtin_amdgcn_logf)
#define LOG2F(x) __builtin_amdgcn_logf(x)
#else
#define LOG2F(x) log2f(x)
#endif

// exp(2*dot) == exp2(dot * 2*log2(e)); we fold sqrt(2*log2(e)) into each z
// at convert time so the MFMA result is already in exp2 domain.
#define PRESCALE 1.6986436005760381f   // sqrt(2*log2(e))

typedef const __attribute__((address_space(1))) void* gas_ptr;
typedef __attribute__((address_space(3))) void* las_ptr;

__device__ __forceinline__ unsigned short f2bf(float f) {
  unsigned u = __float_as_uint(f);
  u += 0x7fffu + ((u >> 16) & 1u);   // RNE
  return (unsigned short)(u >> 16);
}

// ---- K1: f32 -> bf16 conversion with PRESCALE (z -> zb) + zero S and out ----
__global__ void k_convert(const float* __restrict__ z, unsigned short* __restrict__ zb,
                          float* __restrict__ S, float* __restrict__ out) {
  int i = blockIdx.x * blockDim.x + threadIdx.x;  // over N2*KDIM/4
  if (i < N2) S[i] = 0.f;
  if (i == 0) out[0] = 0.f;
  float4 v = reinterpret_cast<const float4*>(z)[i];
  ushort4 o;
  o.x = f2bf(v.x * PRESCALE); o.y = f2bf(v.y * PRESCALE);
  o.z = f2bf(v.z * PRESCALE); o.w = f2bf(v.w * PRESCALE);
  reinterpret_cast<ushort4*>(zb)[i] = o;
}

// ---- K2: fused sim -> exp -> row sums (diagonal masked) ----
// R8: 2-STAGE SOFTWARE PIPELINE on the R7 chassis.
// R7 counters proved zero pipe overlap: MfmaUtil 33% x 89.6us = 29.6us matrix
// busy (== the 33us MFMA floor) and VALUBusy 45% = 40us epilogue; the two run
// strictly SEQUENTIALLY because the epilogue depends on the same tile's acc
// and a wave issues in order -> forced [MFMA burst][VALU burst] alternation,
// phase-locked across the 2 waves/SIMD. Fix: break the dependency. Two named
// accumulator sets (accA/accB, static indexing per rule #20): tile t's MFMAs
// write one while tile t-1's exp2/rowsum epilogue consumes the other, all in
// one basic block, with sched_group_barrier (1 MFMA : 3 VALU) forcing the
// interleave so each ~19cyc MFMA shadow absorbs ~3 epilogue VALU/trans ops.
// Zero-init v_movs removed: the s=0 MFMA takes literal-zero C.
// Chassis unchanged (verified): per-wave private 2x8KB LDS slices, NO
// __syncthreads, counted vmcnt(8), source-side XOR swizzle (conflicts==0),
// afr pinned vs remat (R5/R6 lesson), diag mask, lane reduce + atomics.
__global__ __launch_bounds__(256, 2) void k_main(const unsigned short* __restrict__ zb,
                                                 float* __restrict__ S) {
  __shared__ __align__(16) unsigned short Bs[4][2][WCOLS * KDIM];  // 64 KiB
  const int t    = threadIdx.x;
  const int w    = t >> 6;    // wave = 32-col strip
  const int l    = t & 63;
  const int q    = l >> 4;    // quad within wave
  const int c15  = l & 15;
  const int rg   = blockIdx.x >> 1;
  const int half = blockIdx.x & 1;
  const int rbase = rg * 64;

  // Per-lane DMA source byte offsets within the wave's 8 KB strip (8 issues).
  // Physical granule p = j*64 + l; row=p>>4, pg=p&15; data granule
  // k8 = pg ^ (row&15).
  int srcoff[8];
#pragma unroll
  for (int j = 0; j < 8; ++j) {
    int p   = j * 64 + l;
    int row = p >> 4;
    int pg  = p & 15;
    int k8  = pg ^ (row & 15);
    srcoff[j] = (row * 16 + k8) * 16;   // bytes
  }

  const char* sbase = (const char*)zb + (size_t)(half * NHCOL + w * WCOLS) * KDIM * 2;

  // Prologue: DMA tile 0 into buffer 0.
#pragma unroll
  for (int j = 0; j < 8; ++j)
    __builtin_amdgcn_global_load_lds((gas_ptr)(sbase + srcoff[j]),
                                     (las_ptr)(&Bs[w][0][j * 512]), 16, 0, 0);

  // A fragments (lane holds A[m=lane&15][k=q*8+j]), pinned so the compiler
  // cannot rematerialize them from L2 inside the loop (R5/R6 failure).
  bf16x8 afr[4][4];
#pragma unroll
  for (int m = 0; m < 4; ++m) {
    const unsigned short* ap = zb + (size_t)(rbase + m * 16 + c15) * KDIM + q * 8;
#pragma unroll
    for (int s = 0; s < 4; ++s)
      afr[m][s] = *reinterpret_cast<const bf16x8*>(ap + s * 32);
  }
#pragma unroll
  for (int m = 0; m < 4; ++m)
#pragma unroll
    for (int s = 0; s < 4; ++s)
      asm volatile("" : "+v"(afr[m][s]));

  float rowsum[4][4];
#pragma unroll
  for (int m = 0; m < 4; ++m)
#pragma unroll
    for (int r = 0; r < 4; ++r) rowsum[m][r] = 0.f;

  const int dOff0 = (half * NHCOL + w * WCOLS) - rbase;

  f32x4 accA[4][2], accB[4][2];

// STAGE_P(tile T, cur buf CB, next buf NB, ACC): issue DMA for tile T+1,
// wait only for tile T's 8 loads (counted vmcnt), ds_read swizzled B frags,
// 32 MFMAs s-major into ACC (s=0 takes literal-zero C: no init movs).
#define STAGE_BODY(T, CB, NB, ACC, PREFETCH, VMCNT_ASM)                        \
  {                                                                            \
    if (PREFETCH) {                                                            \
      const char* _src = sbase + (size_t)((T) + 1) * BCOLS * KDIM * 2;         \
      _Pragma("unroll")                                                        \
      for (int j = 0; j < 8; ++j)                                              \
        __builtin_amdgcn_global_load_lds((gas_ptr)(_src + srcoff[j]),          \
                                         (las_ptr)(&Bs[w][NB][j * 512]), 16, 0, 0); \
    }                                                                          \
    asm volatile(VMCNT_ASM ::: "memory");                                      \
    bf16x8 bfr[4][2];                                                          \
    _Pragma("unroll")                                                          \
    for (int s = 0; s < 4; ++s)                                                \
      _Pragma("unroll")                                                        \
      for (int n = 0; n < 2; ++n) {                                            \
        int idx = (n * 16 + c15) * KDIM + (((s * 4 + q) ^ c15) * 8);           \
        bfr[s][n] = *reinterpret_cast<const bf16x8*>(&Bs[w][CB][idx]);         \
      }                                                                        \
    _Pragma("unroll")                                                          \
    for (int m = 0; m < 4; ++m)                                                \
      _Pragma("unroll")                                                        \
      for (int n = 0; n < 2; ++n)                                              \
        ACC[m][n] = __builtin_amdgcn_mfma_f32_16x16x32_bf16(                   \
            afr[m][0], bfr[0][n], (f32x4){0.f, 0.f, 0.f, 0.f}, 0, 0, 0);       \
    _Pragma("unroll")                                                          \
    for (int s = 1; s < 4; ++s)                                                \
      _Pragma("unroll")                                                        \
      for (int m = 0; m < 4; ++m)                                              \
        _Pragma("unroll")                                                      \
        for (int n = 0; n < 2; ++n)                                            \
          ACC[m][n] = __builtin_amdgcn_mfma_f32_16x16x32_bf16(                 \
              afr[m][s], bfr[s][n], ACC[m][n], 0, 0, 0);                       \
  }

#define STAGE_P(T, CB, NB, ACC) STAGE_BODY(T, CB, NB, ACC, 1, "s_waitcnt vmcnt(8)")
#define STAGE_L(T, CB, ACC)     STAGE_BODY(T, CB, 0,  ACC, 0, "s_waitcnt vmcnt(0)")

// Branchless epilogue (single BB so SGB can interleave it with MFMAs):
// fragment (m,n): row = rbase+m*16+q*4+r, col = C0+n*16+c15; diagonal iff
// dOff == (m-n)*16, element masked when c15 == q*4+r.
#define EPI(ACC, IT)                                                           \
  {                                                                            \
    const int _dOff = dOff0 + (IT) * BCOLS;                                    \
    _Pragma("unroll")                                                          \
    for (int m = 0; m < 4; ++m)                                                \
      _Pragma("unroll")                                                        \
      for (int n = 0; n < 2; ++n) {                                            \
        const bool dfrag = (_dOff == (m - n) * 16);                            \
        _Pragma("unroll")                                                      \
        for (int r = 0; r < 4; ++r) {                                          \
          float e = EXP2F(ACC[m][n][r]);                                       \
          if (dfrag && (c15 == q * 4 + r)) e = 0.f;                            \
          rowsum[m][r] += e;                                                   \
        }                                                                      \
      }                                                                        \
  }

// Force 1 MFMA : 3 VALU interleave (epilogue exp2/adds fill each ~19cyc
// MFMA shadow). ds_reads grouped first. Best-effort matching.
#define SGB_INTERLEAVE                                                         \
  {                                                                            \
    __builtin_amdgcn_sched_group_barrier(0x100, 8, 0);   /* 8 DS_READ */       \
    _Pragma("unroll")                                                          \
    for (int u = 0; u < 32; ++u) {                                             \
      __builtin_amdgcn_sched_group_barrier(0x008, 1, 0); /* 1 MFMA  */         \
      __builtin_amdgcn_sched_group_barrier(0x002, 3, 0); /* 3 VALU  */         \
    }                                                                          \
  }

  STAGE_P(0, 0, 1, accA);                    // tile 0 (prefetches tile 1)
#pragma unroll 1
  for (int p = 0; p < NITER / 2 - 1; ++p) {  // tiles 1..62, epilogues 0..61
    const int it = 2 * p;
    STAGE_P(it + 1, 1, 0, accB);
    EPI(accA, it);
    SGB_INTERLEAVE;
    STAGE_P(it + 2, 0, 1, accA);
    EPI(accB, it + 1);
    SGB_INTERLEAVE;
  }
  STAGE_L(NITER - 1, 1, accB);               // tile 63
  EPI(accA, NITER - 2);                      // tile 62
  SGB_INTERLEAVE;
  EPI(accB, NITER - 1);                      // tile 63

#undef STAGE_BODY
#undef STAGE_P
#undef STAGE_L
#undef EPI
#undef SGB_INTERLEAVE

  // reduce across 16 column-lanes (xor 1,2,4,8 stay within quads), then one
  // atomicAdd per row-partial (8 per S element: 2 halves x 4 strips)
#pragma unroll
  for (int m = 0; m < 4; ++m)
#pragma unroll
    for (int r = 0; r < 4; ++r) {
      float v = rowsum[m][r];
      v += __shfl_xor(v, 1);
      v += __shfl_xor(v, 2);
      v += __shfl_xor(v, 4);
      v += __shfl_xor(v, 8);
      if (c15 == 0) atomicAdd(&S[rbase + m * 16 + q * 4 + r], v);
    }
}

// ---- K3: loss_i = log(S_i) - 2*z_i.z_pair(i); mean into out ----
__global__ void k_final(const float* __restrict__ z, const float* __restrict__ S,
                        float* __restrict__ out) {
  __shared__ float red[256];
  int t = threadIdx.x;
  int i = blockIdx.x * 256 + t;
  int j = i ^ NHALF;  // positive pair index
  const float4* zi = reinterpret_cast<const float4*>(z + (size_t)i * KDIM);
  const float4* zj = reinterpret_cast<const float4*>(z + (size_t)j * KDIM);
  float dot = 0.f;
#pragma unroll
  for (int k = 0; k < KDIM / 4; ++k) {
    float4 a = zi[k], b = zj[k];
    dot += a.x * b.x + a.y * b.y + a.z * b.z + a.w * b.w;
  }
  float loss = LOG2F(S[i]) * 0.69314718055994531f - 2.f * dot;
  red[t] = loss;
  __syncthreads();
  for (int o = 128; o > 0; o >>= 1) {
    if (t < o) red[t] += red[t + o];
    __syncthreads();
  }
  if (t == 0) atomicAdd(out, red[0] * (1.f / N2));
}

extern "C" void kernel_launch(void* const* d_in, const int* in_sizes, int n_in,
                              void* d_out, int out_size, void* d_ws, size_t ws_size,
                              hipStream_t stream) {
  const float* z = (const float*)d_in[0];
  float* out = (float*)d_out;
  unsigned short* zb = (unsigned short*)d_ws;                       // 4 MB bf16 copy of z
  float* S = (float*)((char*)d_ws + (size_t)N2 * KDIM * 2);         // 64 KB row sums

  k_convert<<<(N2 * KDIM / 4) / 256, 256, 0, stream>>>(z, zb, S, out);
  k_main<<<(N2 / 64) * 2, 256, 0, stream>>>(zb, S);
  k_final<<<N2 / 256, 256, 0, stream>>>(z, S, out);
}

// Round 9
// 141.642 us; speedup vs baseline: 1.3888x; 1.0199x over previous
//
#include <hip/hip_runtime.h>
#include <hip/hip_bf16.h>

#define N2    16384
#define NHALF 8192
#define KDIM  128
#define WCOLS 32                  // cols per wave-strip per iteration
#define BCOLS 128                 // cols per block per iteration (4 waves)
#define NHCOL 8192                // cols per block (half of N2)
#define NITER (NHCOL / BCOLS)     // 64

using bf16x8 = __attribute__((ext_vector_type(8))) short;
using f32x4  = __attribute__((ext_vector_type(4))) float;

#if __has_builtin(__builtin_amdgcn_exp2f)
#define EXP2F(x) __builtin_amdgcn_exp2f(x)
#else
#define EXP2F(x) exp2f(x)
#endif
#if __has_builtin(__builtin_amdgcn_logf)
#define LOG2F(x) __builtin_amdgcn_logf(x)
#else
#define LOG2F(x) log2f(x)
#endif

// exp(2*dot) == exp2(dot * 2*log2(e)); we fold sqrt(2*log2(e)) into each z
// at convert time so the MFMA result is already in exp2 domain.
#define PRESCALE 1.6986436005760381f   // sqrt(2*log2(e))

typedef const __attribute__((address_space(1))) void* gas_ptr;
typedef __attribute__((address_space(3))) void* las_ptr;

__device__ __forceinline__ unsigned short f2bf(float f) {
  unsigned u = __float_as_uint(f);
  u += 0x7fffu + ((u >> 16) & 1u);   // RNE
  return (unsigned short)(u >> 16);
}

// ---- K1: f32 -> bf16 conversion with PRESCALE (z -> zb) + zero S and out ----
__global__ void k_convert(const float* __restrict__ z, unsigned short* __restrict__ zb,
                          float* __restrict__ S, float* __restrict__ out) {
  int i = blockIdx.x * blockDim.x + threadIdx.x;  // over N2*KDIM/4
  if (i < N2) S[i] = 0.f;
  if (i == 0) out[0] = 0.f;
  float4 v = reinterpret_cast<const float4*>(z)[i];
  ushort4 o;
  o.x = f2bf(v.x * PRESCALE); o.y = f2bf(v.y * PRESCALE);
  o.z = f2bf(v.z * PRESCALE); o.w = f2bf(v.w * PRESCALE);
  reinterpret_cast<ushort4*>(zb)[i] = o;
}

// ---- K2: fused sim -> exp -> full row sums (diagonal INCLUDED) ----
// R9: two changes on the R8 chassis, per the zero-overlap diagnosis
// (MfmaUtil 35% + VALUBusy 48% summed to the wall minus idle -> MFMA and
// VALU phases never overlapped; EPI's wave-uniform diagonal-mask branch
// split it into multiple basic blocks, so sched_group_barrier had no VALU
// to interleave):
//  (1) DIAGONAL REMOVED ALGEBRAICALLY. The row sum now includes j==i; the
//      self-term exp2(sum_k bf16(z_ik*s)^2) is subtracted in k_final from
//      zb (error ~1e-7 relative on S~16384 — far below tolerance). The
//      inner loop has ZERO compares/selects/branches: 32 exp2 + 32 adds.
//  (2) QUARTER-FUSED INTERLEAVE, single BB: each stage runs 4 quarters of
//      [8 exp2+8 adds of tile t-1 (rows m==s)] then [8 MFMAs of tile t
//      (k-group s)], with SGB (VALU,16)(MFMA,8) per quarter. 8 MFMAs = 155
//      pipe-cycles absorb the 80 VALU-issue cycles -> epilogue hidden
//      within one wave; the s=0 EPI also covers ds_read lgkm latency.
// Chassis (verified): per-wave private 2x8KB LDS slices, NO __syncthreads,
// counted vmcnt(8), source-side XOR swizzle (SQ_LDS_BANK_CONFLICT==0),
// afr pinned vs remat (R5/R6 lesson), lane reduce + atomics.
__global__ __launch_bounds__(256, 2) void k_main(const unsigned short* __restrict__ zb,
                                                 float* __restrict__ S) {
  __shared__ __align__(16) unsigned short Bs[4][2][WCOLS * KDIM];  // 64 KiB
  const int t    = threadIdx.x;
  const int w    = t >> 6;    // wave = 32-col strip
  const int l    = t & 63;
  const int q    = l >> 4;    // quad within wave
  const int c15  = l & 15;
  const int rg   = blockIdx.x >> 1;
  const int half = blockIdx.x & 1;
  const int rbase = rg * 64;

  // Per-lane DMA source byte offsets within the wave's 8 KB strip (8 issues).
  // Physical granule p = j*64 + l; row=p>>4, pg=p&15; data granule
  // k8 = pg ^ (row&15).
  int srcoff[8];
#pragma unroll
  for (int j = 0; j < 8; ++j) {
    int p   = j * 64 + l;
    int row = p >> 4;
    int pg  = p & 15;
    int k8  = pg ^ (row & 15);
    srcoff[j] = (row * 16 + k8) * 16;   // bytes
  }

  const char* sbase = (const char*)zb + (size_t)(half * NHCOL + w * WCOLS) * KDIM * 2;
  const size_t TSTRIDE = (size_t)BCOLS * KDIM * 2;   // source advance per tile

  // Prologue: DMA tile 0 into buffer 0.
#pragma unroll
  for (int j = 0; j < 8; ++j)
    __builtin_amdgcn_global_load_lds((gas_ptr)(sbase + srcoff[j]),
                                     (las_ptr)(&Bs[w][0][j * 512]), 16, 0, 0);
  const char* srcNext = sbase + TSTRIDE;             // next tile to prefetch

  // A fragments (lane holds A[m=lane&15][k=q*8+j]), pinned so the compiler
  // cannot rematerialize them from L2 inside the loop (R5/R6 failure).
  bf16x8 afr[4][4];
#pragma unroll
  for (int m = 0; m < 4; ++m) {
    const unsigned short* ap = zb + (size_t)(rbase + m * 16 + c15) * KDIM + q * 8;
#pragma unroll
    for (int s = 0; s < 4; ++s)
      afr[m][s] = *reinterpret_cast<const bf16x8*>(ap + s * 32);
  }
#pragma unroll
  for (int m = 0; m < 4; ++m)
#pragma unroll
    for (int s = 0; s < 4; ++s)
      asm volatile("" : "+v"(afr[m][s]));

  float rowsum[4][4];
#pragma unroll
  for (int m = 0; m < 4; ++m)
#pragma unroll
    for (int r = 0; r < 4; ++r) rowsum[m][r] = 0.f;

  f32x4 accA[4][2], accB[4][2];

// One stage: [optionally prefetch next tile into buffer NB and wait vmcnt(8),
// else drain vmcnt(0)], swizzled ds_read of this tile from buffer CB, then 4
// quarters of { 16 EPI VALU ops (prev tile, rows m==s) ; 8 MFMAs (k-group s) }.
// s==0 MFMAs take literal-zero C (no init movs). Single basic block.
#define STAGE(CB, NB, ACC_W, ACC_R, PRE, DOEPI)                                \
  {                                                                            \
    if (PRE) {                                                                 \
      _Pragma("unroll")                                                        \
      for (int j = 0; j < 8; ++j)                                              \
        __builtin_amdgcn_global_load_lds((gas_ptr)(srcNext + srcoff[j]),       \
                                         (las_ptr)(&Bs[w][NB][j * 512]), 16, 0, 0); \
      srcNext += TSTRIDE;                                                      \
      asm volatile("s_waitcnt vmcnt(8)" ::: "memory");                         \
    } else {                                                                   \
      asm volatile("s_waitcnt vmcnt(0)" ::: "memory");                         \
    }                                                                          \
    bf16x8 bfr[4][2];                                                          \
    _Pragma("unroll")                                                          \
    for (int s = 0; s < 4; ++s)                                                \
      _Pragma("unroll")                                                        \
      for (int n = 0; n < 2; ++n) {                                            \
        int idx = (n * 16 + c15) * KDIM + (((s * 4 + q) ^ c15) * 8);           \
        bfr[s][n] = *reinterpret_cast<const bf16x8*>(&Bs[w][CB][idx]);         \
      }                                                                        \
    _Pragma("unroll")                                                          \
    for (int s = 0; s < 4; ++s) {                                              \
      if (DOEPI) {                                                             \
        _Pragma("unroll")                                                      \
        for (int n = 0; n < 2; ++n)                                            \
          _Pragma("unroll")                                                    \
          for (int r = 0; r < 4; ++r)                                          \
            rowsum[s][r] += EXP2F(ACC_R[s][n][r]);                             \
      }                                                                        \
      if (s == 0) {                                                            \
        _Pragma("unroll")                                                      \
        for (int m = 0; m < 4; ++m)                                            \
          _Pragma("unroll")                                                    \
          for (int n = 0; n < 2; ++n)                                          \
            ACC_W[m][n] = __builtin_amdgcn_mfma_f32_16x16x32_bf16(             \
                afr[m][0], bfr[0][n], (f32x4){0.f, 0.f, 0.f, 0.f}, 0, 0, 0);   \
      } else {                                                                 \
        _Pragma("unroll")                                                      \
        for (int m = 0; m < 4; ++m)                                            \
          _Pragma("unroll")                                                    \
          for (int n = 0; n < 2; ++n)                                          \
            ACC_W[m][n] = __builtin_amdgcn_mfma_f32_16x16x32_bf16(             \
                afr[m][s], bfr[s][n], ACC_W[m][n], 0, 0, 0);                   \
      }                                                                        \
    }                                                                          \
    __builtin_amdgcn_sched_group_barrier(0x100, 8, 0);  /* 8 DS_READ */        \
    _Pragma("unroll")                                                          \
    for (int u = 0; u < 4; ++u) {                                              \
      if (DOEPI) __builtin_amdgcn_sched_group_barrier(0x002, 16, 0);           \
      __builtin_amdgcn_sched_group_barrier(0x008, 8, 0);                       \
    }                                                                          \
  }

  STAGE(0, 1, accA, accA, 1, 0);            // tile 0 (prefetch tile 1)
#pragma unroll 1
  for (int p = 0; p < NITER / 2 - 1; ++p) { // tiles 1..62, epilogues 0..61
    STAGE(1, 0, accB, accA, 1, 1);
    STAGE(0, 1, accA, accB, 1, 1);
  }
  STAGE(1, 0, accB, accA, 0, 1);            // tile 63 MFMA + tile 62 epilogue
#undef STAGE

  // Final epilogue: tile 63 (accB). No mask — diagonal handled in k_final.
#pragma unroll
  for (int m = 0; m < 4; ++m)
#pragma unroll
    for (int n = 0; n < 2; ++n)
#pragma unroll
      for (int r = 0; r < 4; ++r)
        rowsum[m][r] += EXP2F(accB[m][n][r]);

  // reduce across 16 column-lanes (xor 1,2,4,8 stay within quads), then one
  // atomicAdd per row-partial (8 per S element: 2 halves x 4 strips)
#pragma unroll
  for (int m = 0; m < 4; ++m)
#pragma unroll
    for (int r = 0; r < 4; ++r) {
      float v = rowsum[m][r];
      v += __shfl_xor(v, 1);
      v += __shfl_xor(v, 2);
      v += __shfl_xor(v, 4);
      v += __shfl_xor(v, 8);
      if (c15 == 0) atomicAdd(&S[rbase + m * 16 + q * 4 + r], v);
    }
}

// ---- K3: loss_i = log(S_i - exp2(selfdot_bf16)) - 2*z_i.z_pair(i) ----
// S now includes the diagonal term; subtract it here. selfdot is recomputed
// from zb (same prescaled bf16 values the MFMA consumed) — matches the MFMA's
// diagonal contribution to ~1e-7 relative, i.e. ~1e-10 on the final loss.
__global__ void k_final(const float* __restrict__ z, const unsigned short* __restrict__ zb,
                        const float* __restrict__ S, float* __restrict__ out) {
  __shared__ float red[256];
  int t = threadIdx.x;
  int i = blockIdx.x * 256 + t;
  int j = i ^ NHALF;  // positive pair index
  const float4* zi = reinterpret_cast<const float4*>(z + (size_t)i * KDIM);
  const float4* zj = reinterpret_cast<const float4*>(z + (size_t)j * KDIM);
  float dot = 0.f;
#pragma unroll
  for (int k = 0; k < KDIM / 4; ++k) {
    float4 a = zi[k], b = zj[k];
    dot += a.x * b.x + a.y * b.y + a.z * b.z + a.w * b.w;
  }
  // self-dot in the exp2 domain from the prescaled bf16 row
  const bf16x8* zr = reinterpret_cast<const bf16x8*>(zb + (size_t)i * KDIM);
  float d = 0.f;
#pragma unroll
  for (int k = 0; k < KDIM / 8; ++k) {
    bf16x8 v = zr[k];
#pragma unroll
    for (int e = 0; e < 8; ++e) {
      float f = __uint_as_float(((unsigned)(unsigned short)v[e]) << 16);
      d += f * f;
    }
  }
  float loss = LOG2F(S[i] - EXP2F(d)) * 0.69314718055994531f - 2.f * dot;
  red[t] = loss;
  __syncthreads();
  for (int o = 128; o > 0; o >>= 1) {
    if (t < o) red[t] += red[t + o];
    __syncthreads();
  }
  if (t == 0) atomicAdd(out, red[0] * (1.f / N2));
}

extern "C" void kernel_launch(void* const* d_in, const int* in_sizes, int n_in,
                              void* d_out, int out_size, void* d_ws, size_t ws_size,
                              hipStream_t stream) {
  const float* z = (const float*)d_in[0];
  float* out = (float*)d_out;
  unsigned short* zb = (unsigned short*)d_ws;                       // 4 MB bf16 copy of z
  float* S = (float*)((char*)d_ws + (size_t)N2 * KDIM * 2);         // 64 KB row sums

  k_convert<<<(N2 * KDIM / 4) / 256, 256, 0, stream>>>(z, zb, S, out);
  k_main<<<(N2 / 64) * 2, 256, 0, stream>>>(zb, S);
  k_final<<<N2 / 256, 256, 0, stream>>>(z, zb, S, out);
}